// Round 5
// baseline (379.286 us; speedup 1.0000x reference)
//
#include <hip/hip_runtime.h>
#include <hip/hip_fp16.h>
#include <stdint.h>

static constexpr int CI = 16;
static constexpr int CO = 32;
static constexpr int H  = 300000;
static constexpr int K  = 27;
static constexpr float BN_EPS = 1e-5f;

// ---------- f16 helpers ----------
typedef _Float16 h2_t __attribute__((ext_vector_type(2)));

__device__ __forceinline__ unsigned int pack_f16(float lo, float hi) {
    union { h2_t h; unsigned int u; } v;
    v.h[0] = (_Float16)lo;
    v.h[1] = (_Float16)hi;
    return v.u;
}

// acc += a.lo*b.lo + a.hi*b.hi  (v_dot2_f32_f16)
__device__ __forceinline__ float dot2f(unsigned int a, unsigned int b, float c) {
#if __has_builtin(__builtin_amdgcn_fdot2)
    union { unsigned int u; h2_t h; } ua, ub;
    ua.u = a; ub.u = b;
    return __builtin_amdgcn_fdot2(ua.h, ub.h, c, false);
#else
    union { unsigned int u; h2_t h; } ua, ub;
    ua.u = a; ub.u = b;
    float r = fmaf((float)ua.h[0], (float)ub.h[0], c);
    return fmaf((float)ua.h[1], (float)ub.h[1], r);
#endif
}

// ---------- kernel 1: fused prep ----------
// x fp32 (CI,H) -> xTp f16-pair rows (H x 8 dwords, 32 B/row);
// w fp32 (o,i,k) -> wp[(k*32+o)*8+j] = (w[o,2j,k], w[o,2j+1,k]) f16 pairs;
// zero stats[64].
__global__ __launch_bounds__(256) void prep(const float* __restrict__ x,
                                            const float* __restrict__ w,
                                            unsigned int* __restrict__ xTp,
                                            unsigned int* __restrict__ wp,
                                            float* __restrict__ stats) {
    int h = blockIdx.x * 256 + threadIdx.x;
    if (h < H) {
        unsigned int r[8];
        #pragma unroll
        for (int j = 0; j < 8; ++j)
            r[j] = pack_f16(x[(size_t)(2 * j) * H + h], x[(size_t)(2 * j + 1) * H + h]);
        uint4* dst = reinterpret_cast<uint4*>(xTp + (size_t)h * 8);
        dst[0] = make_uint4(r[0], r[1], r[2], r[3]);
        dst[1] = make_uint4(r[4], r[5], r[6], r[7]);
    }
    if (blockIdx.x == 0) {
        for (int idx = threadIdx.x; idx < K * CO * 8; idx += 256) {
            int j = idx & 7;
            int o = (idx >> 3) & 31;
            int k = idx >> 8;
            float lo = w[((size_t)o * CI + 2 * j) * K + k];
            float hi = w[((size_t)o * CI + 2 * j + 1) * K + k];
            wp[idx] = pack_f16(lo, hi);
        }
        if (threadIdx.x < 64) stats[threadIdx.x] = 0.f;   // gsum[32] ++ gsq[32]
    }
}

// ---------- kernel 2: gathered conv (f16 dot2) + fused BN stats ----------
// R0 structure (2 threads/h split by output halves, acc[16], 1-deep row
// pipeline) with ZERO LDS. Cross-round occupancy data (R0/R1/R2) showed
// resident blocks/CU == floor(64KB / LDS_block): the neighbor-staging LDS
// was HALVING residency in this latency-bound kernel. Each neigh value is
// consumed exactly once and each lane's 27 ints live in ~2 cache lines that
// stay L1-hot across the k-loop -> direct global loads lose nothing.
__global__ __launch_bounds__(256) void conv(const unsigned int* __restrict__ xTp,
                                            const unsigned int* __restrict__ wp,
                                            const int* __restrict__ neigh,
                                            float* __restrict__ out,
                                            float* __restrict__ stats) {
    const int t    = threadIdx.x;
    const int hl   = t & 127;
    const int half = __builtin_amdgcn_readfirstlane(t >> 7);   // wave-uniform 0/1
    const int h    = blockIdx.x * 128 + hl;

    float acc[16];
    #pragma unroll
    for (int o = 0; o < 16; ++o) acc[o] = 0.f;

    if (h < H) {
        const int* np = neigh + (size_t)h * K;      // per-lane row, L1-hot after k=0
        const unsigned int* wh = wp + half * 128;   // this half's 16 outputs x 8 pairs

        // prologue: prefetch k = 0
        int idx = np[0];
        const uint4* p0 = reinterpret_cast<const uint4*>(
            xTp + (size_t)(idx < 0 ? 0 : idx) * 8);
        uint4 a = p0[0];
        uint4 b = p0[1];

        for (int k = 0; k < K; ++k) {
            const int nidx = (k + 1 < K) ? np[k + 1] : 0;
            const uint4* p1 = reinterpret_cast<const uint4*>(
                xTp + (size_t)(nidx < 0 ? 0 : nidx) * 8);
            uint4 na = p1[0];
            uint4 nb = p1[1];

            if (idx < 0) {                      // cndmask zero for invalid neighbor
                a.x = a.y = a.z = a.w = 0u;
                b.x = b.y = b.z = b.w = 0u;
            }

            const unsigned int* wk = wh + k * 256;   // wave-uniform -> scalar loads
            #pragma unroll
            for (int o = 0; o < 16; ++o) {
                float s = acc[o];
                s = dot2f(a.x, wk[o * 8 + 0], s);
                s = dot2f(a.y, wk[o * 8 + 1], s);
                s = dot2f(a.z, wk[o * 8 + 2], s);
                s = dot2f(a.w, wk[o * 8 + 3], s);
                s = dot2f(b.x, wk[o * 8 + 4], s);
                s = dot2f(b.y, wk[o * 8 + 5], s);
                s = dot2f(b.z, wk[o * 8 + 6], s);
                s = dot2f(b.w, wk[o * 8 + 7], s);
                acc[o] = s;
            }

            idx = nidx; a = na; b = nb;
        }
        #pragma unroll
        for (int o = 0; o < 16; ++o)
            out[(size_t)(half * 16 + o) * H + h] = acc[o];   // coalesced over h
    }

    // fused BN statistics: butterfly per output, one atomic per wave per output
    const unsigned lane = t & 63u;
    float mySum = 0.f, mySq = 0.f;
    #pragma unroll
    for (int o = 0; o < 16; ++o) {
        float v = acc[o];
        float q = v * v;
        #pragma unroll
        for (int d = 32; d > 0; d >>= 1) {
            v += __shfl_xor(v, d, 64);
            q += __shfl_xor(q, d, 64);
        }
        if (lane == (unsigned)o) { mySum = v; mySq = q; }
    }
    if (lane < 16u) {
        atomicAdd(&stats[half * 16 + lane], mySum);        // gsum
        atomicAdd(&stats[32 + half * 16 + lane], mySq);    // gsq
    }
}

// ---------- kernel 3: BN apply (scale/shift recomputed per thread from stats) ----------
__global__ __launch_bounds__(256) void bn_apply(float* __restrict__ out,
                                                const float* __restrict__ stats,
                                                const float* __restrict__ gamma,
                                                const float* __restrict__ beta) {
    size_t t = (size_t)blockIdx.x * 256 + threadIdx.x;
    size_t base = t * 4;
    if (base >= (size_t)CO * H) return;
    int o = (int)(base / (size_t)H);     // H % 4 == 0 -> float4 never crosses channels
    const float invH = 1.f / (float)H;
    float m   = stats[o] * invH;
    float var = stats[32 + o] * invH - m * m;
    float inv = rsqrtf(var + BN_EPS);
    float sc  = gamma[o] * inv;
    float sh  = beta[o] - m * sc;
    float4* p = reinterpret_cast<float4*>(out + base);
    float4 q = *p;
    q.x = q.x * sc + sh;
    q.y = q.y * sc + sh;
    q.z = q.z * sc + sh;
    q.w = q.w * sc + sh;
    *p = q;
}

// ---------- launch ----------
extern "C" void kernel_launch(void* const* d_in, const int* in_sizes, int n_in,
                              void* d_out, int out_size, void* d_ws, size_t ws_size,
                              hipStream_t stream) {
    const float* x     = (const float*)d_in[0];   // fp32 (1,CI,H,1)
    const float* w     = (const float*)d_in[1];   // fp32 (CO,CI,K)
    const float* gamma = (const float*)d_in[2];   // fp32 (CO)
    const float* beta  = (const float*)d_in[3];   // fp32 (CO)
    const int*   neigh = (const int*)d_in[4];     // int32 (H,K)
    float*       out   = (float*)d_out;           // fp32 (CO,H)

    char* ws = (char*)d_ws;
    const size_t XT_OFF    = 0;                    // H*8*4   = 9,600,000 B
    const size_t WP_OFF    = 9600000;              // 6912*4  = 27,648 B
    const size_t STATS_OFF = 9627648;              // 64 floats
    unsigned int* xTp   = (unsigned int*)(ws + XT_OFF);
    unsigned int* wp    = (unsigned int*)(ws + WP_OFF);
    float*        stats = (float*)(ws + STATS_OFF);

    const int HBP = (H + 255) / 256;               // 1172 (prep)
    prep<<<HBP, 256, 0, stream>>>(x, w, xTp, wp, stats);

    const int HBC = (H + 127) / 128;               // 2344 (conv: 128 h/block, zero LDS)
    conv<<<HBC, 256, 0, stream>>>(xTp, wp, neigh, out, stats);

    const int NBN = (CO * H / 4 + 255) / 256;      // 9375
    bn_apply<<<NBN, 256, 0, stream>>>(out, stats, gamma, beta);
}

// Round 6
// 377.894 us; speedup vs baseline: 1.0037x; 1.0037x over previous
//
#include <hip/hip_runtime.h>
#include <hip/hip_fp16.h>
#include <stdint.h>

static constexpr int CI = 16;
static constexpr int CO = 32;
static constexpr int H  = 300000;
static constexpr int K  = 27;
static constexpr float BN_EPS = 1e-5f;

// ---------- f16 helpers ----------
typedef _Float16 h2_t __attribute__((ext_vector_type(2)));

__device__ __forceinline__ unsigned int pack_f16(float lo, float hi) {
    union { h2_t h; unsigned int u; } v;
    v.h[0] = (_Float16)lo;
    v.h[1] = (_Float16)hi;
    return v.u;
}

// acc += a.lo*b.lo + a.hi*b.hi  (v_dot2_f32_f16)
__device__ __forceinline__ float dot2f(unsigned int a, unsigned int b, float c) {
#if __has_builtin(__builtin_amdgcn_fdot2)
    union { unsigned int u; h2_t h; } ua, ub;
    ua.u = a; ub.u = b;
    return __builtin_amdgcn_fdot2(ua.h, ub.h, c, false);
#else
    union { unsigned int u; h2_t h; } ua, ub;
    ua.u = a; ub.u = b;
    float r = fmaf((float)ua.h[0], (float)ub.h[0], c);
    return fmaf((float)ua.h[1], (float)ub.h[1], r);
#endif
}

// ---------- kernel 1: fused prep ----------
__global__ __launch_bounds__(256) void prep(const float* __restrict__ x,
                                            const float* __restrict__ w,
                                            unsigned int* __restrict__ xTp,
                                            unsigned int* __restrict__ wp,
                                            float* __restrict__ stats) {
    int h = blockIdx.x * 256 + threadIdx.x;
    if (h < H) {
        unsigned int r[8];
        #pragma unroll
        for (int j = 0; j < 8; ++j)
            r[j] = pack_f16(x[(size_t)(2 * j) * H + h], x[(size_t)(2 * j + 1) * H + h]);
        uint4* dst = reinterpret_cast<uint4*>(xTp + (size_t)h * 8);
        dst[0] = make_uint4(r[0], r[1], r[2], r[3]);
        dst[1] = make_uint4(r[4], r[5], r[6], r[7]);
    }
    if (blockIdx.x == 0) {
        for (int idx = threadIdx.x; idx < K * CO * 8; idx += 256) {
            int j = idx & 7;
            int o = (idx >> 3) & 31;
            int k = idx >> 8;
            float lo = w[((size_t)o * CI + 2 * j) * K + k];
            float hi = w[((size_t)o * CI + 2 * j + 1) * K + k];
            wp[idx] = pack_f16(lo, hi);
        }
        if (threadIdx.x < 64) stats[threadIdx.x] = 0.f;   // gsum[32] ++ gsq[32]
    }
}

// One k-phase: stage neigh cols [C0, C0+CNT) for the block's 256 h into LDS
// (coalesced-ish 56 B runs, read once), then run the dual-stream 1-deep
// pipelined gather+dot2 loop for those k. Called under UNIFORM control flow.
template<int C0, int CNT>
__device__ __forceinline__ void conv_phase(int base, int t, int tl,
                                           const unsigned int* __restrict__ xTp,
                                           const unsigned int* __restrict__ wh,
                                           const int* __restrict__ neigh,
                                           int* snb,               // [256*14]
                                           float (&acc0)[16], float (&acc1)[16]) {
    __syncthreads();                       // prior phase's snb reads complete
    {
        const int total = 256 * CNT;
        #pragma unroll 1
        for (int idx = t; idx < total; idx += 256) {
            int hh = idx / CNT;            // CNT constexpr -> magic-mul
            int ks = idx - hh * CNT;
            int gr = base + hh;
            snb[hh * 14 + ks] = (gr < H)
                ? neigh[(size_t)gr * K + C0 + ks]   // plain load: lines shared across phases
                : -1;
        }
    }
    __syncthreads();

    const int* np0 = &snb[tl * 14];
    const int* np1 = &snb[(128 + tl) * 14];

    // prologue: first row of each stream in flight
    int i0 = np0[0], i1 = np1[0];
    const uint4* q0 = reinterpret_cast<const uint4*>(xTp + (size_t)(i0 < 0 ? 0 : i0) * 8);
    uint4 a0 = q0[0], b0 = q0[1];
    const uint4* q1 = reinterpret_cast<const uint4*>(xTp + (size_t)(i1 < 0 ? 0 : i1) * 8);
    uint4 a1 = q1[0], b1 = q1[1];

    #pragma unroll 1
    for (int kk = 0; kk < CNT; ++kk) {
        const bool more = (kk + 1 < CNT);
        int n0 = more ? np0[kk + 1] : 0;
        int n1 = more ? np1[kk + 1] : 0;
        const uint4* p0 = reinterpret_cast<const uint4*>(xTp + (size_t)(n0 < 0 ? 0 : n0) * 8);
        uint4 c0 = p0[0], d0 = p0[1];
        const uint4* p1 = reinterpret_cast<const uint4*>(xTp + (size_t)(n1 < 0 ? 0 : n1) * 8);
        uint4 c1 = p1[0], d1 = p1[1];

        if (i0 < 0) { a0.x = a0.y = a0.z = a0.w = 0u; b0.x = b0.y = b0.z = b0.w = 0u; }
        if (i1 < 0) { a1.x = a1.y = a1.z = a1.w = 0u; b1.x = b1.y = b1.z = b1.w = 0u; }

        const unsigned int* wk = wh + (C0 + kk) * 256;   // wave-uniform -> s_load
        #pragma unroll
        for (int o = 0; o < 16; ++o) {
            float s0 = acc0[o], s1 = acc1[o];
            unsigned int w0 = wk[o * 8 + 0], w1 = wk[o * 8 + 1];
            unsigned int w2 = wk[o * 8 + 2], w3 = wk[o * 8 + 3];
            unsigned int w4 = wk[o * 8 + 4], w5 = wk[o * 8 + 5];
            unsigned int w6 = wk[o * 8 + 6], w7 = wk[o * 8 + 7];
            s0 = dot2f(a0.x, w0, s0);  s1 = dot2f(a1.x, w0, s1);
            s0 = dot2f(a0.y, w1, s0);  s1 = dot2f(a1.y, w1, s1);
            s0 = dot2f(a0.z, w2, s0);  s1 = dot2f(a1.z, w2, s1);
            s0 = dot2f(a0.w, w3, s0);  s1 = dot2f(a1.w, w3, s1);
            s0 = dot2f(b0.x, w4, s0);  s1 = dot2f(b1.x, w4, s1);
            s0 = dot2f(b0.y, w5, s0);  s1 = dot2f(b1.y, w5, s1);
            s0 = dot2f(b0.z, w6, s0);  s1 = dot2f(b1.z, w6, s1);
            s0 = dot2f(b0.w, w7, s0);  s1 = dot2f(b1.w, w7, s1);
            acc0[o] = s0; acc1[o] = s1;
        }
        i0 = n0; a0 = c0; b0 = d0;
        i1 = n1; a1 = c1; b1 = d1;
    }
}

// ---------- kernel 2: gathered conv (f16 dot2) + fused BN stats ----------
// TWO independent h-streams per thread (h0 = base+tl, h1 = base+128+tl), each
// with the R0-proven 1-deep prefetch -> 2 rows in flight per thread (double
// the per-CU outstanding gathers at unchanged ~16 waves/CU; R5 showed the
// fabric sustains 2.9 TB/s vs R0's 1.75, i.e. headroom exists). Half-split
// outputs (waves 0-1: o<16, waves 2-3: o>=16) keeps weights wave-uniform and
// gather dup at the proven L1-hit x2. Block covers 256 h; neigh staged in two
// k-phases so LDS stays at 14336 B. launch_bounds(256,4): VGPR budget 128.
__global__ __launch_bounds__(256, 4) void conv(const unsigned int* __restrict__ xTp,
                                               const unsigned int* __restrict__ wp,
                                               const int* __restrict__ neigh,
                                               float* __restrict__ out,
                                               float* __restrict__ stats) {
    __shared__ int snb[256 * 14];                       // 14336 B
    const int t    = threadIdx.x;
    const int tl   = t & 127;
    const int half = __builtin_amdgcn_readfirstlane(t >> 7);   // wave-uniform 0/1
    const int base = blockIdx.x * 256;
    const int h0   = base + tl;                          // always < H (grid exact)
    const int h1   = base + 128 + tl;                    // may exceed H in last block

    float acc0[16], acc1[16];
    #pragma unroll
    for (int o = 0; o < 16; ++o) { acc0[o] = 0.f; acc1[o] = 0.f; }

    const unsigned int* wh = wp + half * 128;            // this half's 16 outputs

    conv_phase<0, 14>(base, t, tl, xTp, wh, neigh, snb, acc0, acc1);
    conv_phase<14, 13>(base, t, tl, xTp, wh, neigh, snb, acc0, acc1);

    if (h0 < H) {
        #pragma unroll
        for (int o = 0; o < 16; ++o)
            out[(size_t)(half * 16 + o) * H + h0] = acc0[o];   // coalesced over h
    }
    if (h1 < H) {
        #pragma unroll
        for (int o = 0; o < 16; ++o)
            out[(size_t)(half * 16 + o) * H + h1] = acc1[o];
    }

    // fused BN statistics: butterfly per output, one atomic per wave per output.
    // Invalid h1 has all-zero acc1 (snb staged -1) -> contributes exact zeros.
    const unsigned lane = t & 63u;
    float mySum = 0.f, mySq = 0.f;
    #pragma unroll
    for (int o = 0; o < 16; ++o) {
        float v = acc0[o] + acc1[o];
        float q = acc0[o] * acc0[o] + acc1[o] * acc1[o];
        #pragma unroll
        for (int d = 32; d > 0; d >>= 1) {
            v += __shfl_xor(v, d, 64);
            q += __shfl_xor(q, d, 64);
        }
        if (lane == (unsigned)o) { mySum = v; mySq = q; }
    }
    if (lane < 16u) {
        atomicAdd(&stats[half * 16 + lane], mySum);        // gsum
        atomicAdd(&stats[32 + half * 16 + lane], mySq);    // gsq
    }
}

// ---------- kernel 3: BN apply (scale/shift recomputed per thread from stats) ----------
__global__ __launch_bounds__(256) void bn_apply(float* __restrict__ out,
                                                const float* __restrict__ stats,
                                                const float* __restrict__ gamma,
                                                const float* __restrict__ beta) {
    size_t t = (size_t)blockIdx.x * 256 + threadIdx.x;
    size_t base = t * 4;
    if (base >= (size_t)CO * H) return;
    int o = (int)(base / (size_t)H);     // H % 4 == 0 -> float4 never crosses channels
    const float invH = 1.f / (float)H;
    float m   = stats[o] * invH;
    float var = stats[32 + o] * invH - m * m;
    float inv = rsqrtf(var + BN_EPS);
    float sc  = gamma[o] * inv;
    float sh  = beta[o] - m * sc;
    float4* p = reinterpret_cast<float4*>(out + base);
    float4 q = *p;
    q.x = q.x * sc + sh;
    q.y = q.y * sc + sh;
    q.z = q.z * sc + sh;
    q.w = q.w * sc + sh;
    *p = q;
}

// ---------- launch ----------
extern "C" void kernel_launch(void* const* d_in, const int* in_sizes, int n_in,
                              void* d_out, int out_size, void* d_ws, size_t ws_size,
                              hipStream_t stream) {
    const float* x     = (const float*)d_in[0];   // fp32 (1,CI,H,1)
    const float* w     = (const float*)d_in[1];   // fp32 (CO,CI,K)
    const float* gamma = (const float*)d_in[2];   // fp32 (CO)
    const float* beta  = (const float*)d_in[3];   // fp32 (CO)
    const int*   neigh = (const int*)d_in[4];     // int32 (H,K)
    float*       out   = (float*)d_out;           // fp32 (CO,H)

    char* ws = (char*)d_ws;
    const size_t XT_OFF    = 0;                    // H*8*4   = 9,600,000 B
    const size_t WP_OFF    = 9600000;              // 6912*4  = 27,648 B
    const size_t STATS_OFF = 9627648;              // 64 floats
    unsigned int* xTp   = (unsigned int*)(ws + XT_OFF);
    unsigned int* wp    = (unsigned int*)(ws + WP_OFF);
    float*        stats = (float*)(ws + STATS_OFF);

    const int HBP = (H + 255) / 256;               // 1172 (prep)
    prep<<<HBP, 256, 0, stream>>>(x, w, xTp, wp, stats);

    const int HBC = (H + 255) / 256;               // 1172 (conv: 256 h/block, 2 streams/thread)
    conv<<<HBC, 256, 0, stream>>>(xTp, wp, neigh, out, stats);

    const int NBN = (CO * H / 4 + 255) / 256;      // 9375
    bn_apply<<<NBN, 256, 0, stream>>>(out, stats, gamma, beta);
}